// Round 5
// baseline (272.777 us; speedup 1.0000x reference)
//
#include <hip/hip_runtime.h>
#include <float.h>

// PQHead forward: out[b, m*6+d] = codebooks[m, argmax_k dot(x[b,m,:], cb[m,k,:]), d]
// (straight-through estimator: forward value of quant is exactly `discrete`)
//
// R11: persistent grid-stride blocks, R10 inner structure unchanged.
//  - R10 post-mortem: VALU busy 46->34.5us moved wall only 107->102.5.
//    Wall is set by per-block stall overhead paid 16x per CU: cb prologue,
//    cold stage-0 vmcnt drain, block turnover. Amortize via persistence.
//  - Sweep-shape theory (explains R8): thrash came from 1024 blocks owning
//    scattered contiguous 64-row spans (instantaneous window = whole array).
//    Grid-stride keeps all blocks marching through consecutive 24 MB row
//    slices in lockstep -> L3 window ~48 MB, R6-like traffic. TRIPWIRE:
//    FETCH/WRITE must stay ~50/98 MB.
//  - Grid 1024 = 512 bx x 2 mhalf; 4 blocks/CU (96 KiB LDS); 4 iterations,
//    8 stages/block, cb loaded once, 7/8 stages have warm prefetch.
//  - Select (R9/R10, proven): pk-max tree + DPP quad-max + epsilon-match
//    mask; popcount==1 -> ctz; else quad-uniform exact fp64 fallback.

typedef float v2f __attribute__((ext_vector_type(2)));

#define BATCH 32768
#define DIM   768
#define K_CB  32
#define D_SUB 6
#define BROWS 16               // rows per block per iteration
#define RSTG  8                // rows per LDS stage
#define GX    512              // blocks along batch
#define NITER (BATCH/(GX*BROWS))   // 4 iterations
#define NSTGT (NITER*2)        // 8 total stages per block
#define RSPAN (GX*BROWS)       // 8192-row stride between iterations
#define HALFF 384              // floats per half row (64 m * 6)
#define STGF  (RSTG*HALFF)     // 3072 floats = 12 KiB per buffer
#define EPS_TIE 1e-5f

#define DPP_XOR1 0xB1          // quad_perm [1,0,3,2]
#define DPP_XOR2 0x4E          // quad_perm [2,3,0,1]

template<int CTRL>
__device__ __forceinline__ float dppf(float v) {
    return __int_as_float(__builtin_amdgcn_update_dpp(
        0, __float_as_int(v), CTRL, 0xF, 0xF, true));
}
template<int CTRL>
__device__ __forceinline__ int dppi(int v) {
    return __builtin_amdgcn_update_dpp(0, v, CTRL, 0xF, 0xF, true);
}

__device__ __forceinline__ int stage_row(int bx, int g) {
    // stage g (0..7): iteration g>>1, half-stage g&1
    return bx * BROWS + (g >> 1) * RSPAN + (g & 1) * RSTG;
}

__global__ __launch_bounds__(256, 4)
void pq_head_kernel(const float* __restrict__ x,
                    const float* __restrict__ cb,
                    float* __restrict__ out) {
    __shared__ float xs[2][STGF];   // 24 KiB double buffer

    const int t     = threadIdx.x;
    const int kq    = t & 3;        // k-quarter (lane within quad)
    const int mloc  = t >> 2;       // 0..63
    const int mhalf = blockIdx.y;   // 0/1
    const int m     = mhalf * 64 + mloc;
    const int bx    = blockIdx.x;

    // Load this lane's 8 codebook rows ONCE (48 floats, 192-B aligned) and
    // pack code-pairs into v2f: cpk[p][e] = (cb[2p][e], cb[2p+1][e]).
    v2f cpk[4][D_SUB];
    {
        float cc[48];
        const float4* cb4 = reinterpret_cast<const float4*>(
            cb + ((size_t)m * K_CB + (size_t)kq * 8) * D_SUB);
        #pragma unroll
        for (int i = 0; i < 12; ++i) {
            float4 v = cb4[i];
            cc[4*i+0]=v.x; cc[4*i+1]=v.y; cc[4*i+2]=v.z; cc[4*i+3]=v.w;
        }
        #pragma unroll
        for (int p = 0; p < 4; ++p)
            #pragma unroll
            for (int e = 0; e < D_SUB; ++e)
                cpk[p][e] = (v2f){cc[(2*p)*D_SUB + e], cc[(2*p+1)*D_SUB + e]};
    }

    const float* xh = x   + (size_t)mhalf * HALFF;  // half-row base
    float*       oh = out + (size_t)mhalf * HALFF;

    // Stage-invariant (row, col) for the coalesced stage load.
    int pr[3], pc[3];
    #pragma unroll
    for (int i = 0; i < 3; ++i) {
        int f = (i * 256 + t) * 4;          // float index within stage (<3072)
        pr[i] = f / HALFF;
        pc[i] = f - pr[i] * HALFF;
    }

    // Prefetch stage 0 (3 x dwordx4 per thread, fully coalesced).
    float4 pf[3];
    {
        int rb = stage_row(bx, 0);
        #pragma unroll
        for (int i = 0; i < 3; ++i)
            pf[i] = *reinterpret_cast<const float4*>(
                xh + (size_t)(rb + pr[i]) * DIM + pc[i]);
    }

    for (int g = 0; g < NSTGT; ++g) {
        float* buf = xs[g & 1];
        #pragma unroll
        for (int i = 0; i < 3; ++i)
            *reinterpret_cast<float4*>(&buf[(i * 256 + t) * 4]) = pf[i];
        __syncthreads();   // writers of buf done; stage g+1 writes the OTHER buffer

        if (g + 1 < NSTGT) {                // prefetch next stage; consumer is
            int rb = stage_row(bx, g + 1);  // a ds_write past this stage's compute
            #pragma unroll
            for (int i = 0; i < 3; ++i)
                pf[i] = *reinterpret_cast<const float4*>(
                    xh + (size_t)(rb + pr[i]) * DIM + pc[i]);
        }

        const int srow = stage_row(bx, g);  // first batch-row of this stage

        // ---- phase A: 8 winner computations -> kg8[] ----
        int kg8[RSTG];
        #pragma unroll
        for (int r = 0; r < RSTG; ++r) {
            const float* xr = &buf[r * HALFF + mloc * D_SUB];  // quad-broadcast
            float2 x01 = *reinterpret_cast<const float2*>(xr);
            float2 x23 = *reinterpret_cast<const float2*>(xr + 2);
            float2 x45 = *reinterpret_cast<const float2*>(xr + 4);
            float xv[6] = {x01.x, x01.y, x23.x, x23.y, x45.x, x45.y};
            v2f xxe[6];
            #pragma unroll
            for (int e = 0; e < 6; ++e) xxe[e] = (v2f){xv[e], xv[e]};

            // 8 packed dots, kept live in acc[4].
            v2f acc[4];
            #pragma unroll
            for (int p = 0; p < 4; ++p) {
                v2f a = cpk[p][0] * xxe[0];
                #pragma unroll
                for (int e = 1; e < 6; ++e)
                    a = __builtin_elementwise_fma(cpk[p][e], xxe[e], a);
                acc[p] = a;
            }

            // Quad max via pk-max tree + 2 DPP merges (pure VALU, ~8 ops).
            v2f t0 = __builtin_elementwise_max(acc[0], acc[1]);
            v2f t1 = __builtin_elementwise_max(acc[2], acc[3]);
            v2f t2 = __builtin_elementwise_max(t0, t1);
            float best1 = fmaxf(t2.x, t2.y);
            best1 = fmaxf(best1, dppf<DPP_XOR1>(best1));
            best1 = fmaxf(best1, dppf<DPP_XOR2>(best1));

            // Epsilon-match mask: bit j set iff dot_j > best1 - 1e-5.
            const float thr = best1 - EPS_TIE;
            int msk = 0;
            #pragma unroll
            for (int p = 0; p < 4; ++p) {
                if (acc[p].x > thr) msk |= 1 << (2*p);
                if (acc[p].y > thr) msk |= 1 << (2*p+1);
            }
            int full = msk << (kq * 8);
            full |= dppi<DPP_XOR1>(full);
            full |= dppi<DPP_XOR2>(full);   // quad-uniform 32-bit mask

            int kg;
            if (__builtin_popcount(full) == 1) {
                // Unique near-max => it IS the strict argmax.
                kg = __builtin_ctz(full);
            } else {
                // Ambiguous within 1e-5 (incl. exact ties): exact fp64 argmax,
                // first-wins — matches jnp.argmax. Quad-uniform branch.
                const float* crow = cb + (size_t)m * K_CB * D_SUB;
                double db = -1e300; int dkg = 0;
                for (int k2 = 0; k2 < K_CB; ++k2) {
                    double sa = 0.0;
                    for (int e = 0; e < 6; ++e)
                        sa = fma((double)crow[k2*6+e], (double)xv[e], sa);
                    if (sa > db) { db = sa; dkg = k2; }
                }
                kg = dkg;
            }
            kg8[r] = kg;
        }

        // ---- phase B: 8 independent winner gathers (cb is L1/L2-hot) ----
        const bool act = (kq < 3);
        float2 gv[RSTG];
        if (act) {
            #pragma unroll
            for (int r = 0; r < RSTG; ++r)
                gv[r] = *(reinterpret_cast<const float2*>(
                    cb + ((size_t)m * K_CB + (size_t)kg8[r]) * D_SUB) + kq);
        }

        __builtin_amdgcn_sched_barrier(0);  // keep all gathers above all stores

        // ---- phase C: 8 coalesced float2 stores (48/64 lanes -> full lines) ----
        if (act) {
            #pragma unroll
            for (int r = 0; r < RSTG; ++r) {
                float* dst = oh + (size_t)(srow + r) * DIM + mloc * D_SUB;
                *(reinterpret_cast<float2*>(dst) + kq) = gv[r];
            }
        }
    }
}

extern "C" void kernel_launch(void* const* d_in, const int* in_sizes, int n_in,
                              void* d_out, int out_size, void* d_ws, size_t ws_size,
                              hipStream_t stream) {
    const float* x  = (const float*)d_in[0];   // (32768, 768) fp32
    const float* cb = (const float*)d_in[1];   // (128, 32, 6) fp32
    float* out = (float*)d_out;                // (32768, 768) fp32

    dim3 grid(GX, 2);              // 512 x 2 = 1024 persistent blocks (4/CU)
    dim3 block(256);               // 64 m x 4 k-quarters
    hipLaunchKernelGGL(pq_head_kernel, grid, block, 0, stream, x, cb, out);
}

// Round 6
// 232.815 us; speedup vs baseline: 1.1716x; 1.1716x over previous
//
#include <hip/hip_runtime.h>
#include <float.h>

// PQHead forward: out[b, m*6+d] = codebooks[m, argmax_k dot(x[b,m,:], cb[m,k,:]), d]
// (straight-through estimator: forward value of quant is exactly `discrete`)
//
// R12: async LDS staging + counted-vmcnt barrier (T3/T4 transfer).
//  - R11 post-mortem: persistent/wide blocks ALWAYS thrash (R8: 409 MB,
//    R11: 356 MB). 4096 short in-order blocks self-synchronize into a
//    ~50 MB sliding L3 window. Keep 4096 x 16-row sweep shape. Final.
//  - R10's stall: __syncthreads() makes hipcc emit s_waitcnt vmcnt(0)
//    before s_barrier -> every stage waits for phase-B gathers AND
//    phase-C store ACKs (~300-900cy) on the critical path of all waves.
//  - Fix: x staged via global_load_lds width=16 (no VGPR round trip, LDS
//    dest is wave-uniform base + lane*16 -> our linear layout matches);
//    in-loop barrier = s_waitcnt vmcnt(16) + raw s_barrier. Per stage:
//    3 gloads (oldest) + 8 gathers + 8 stores (younger) issued => in-order
//    vmcnt retirement makes vmcnt(16) retire exactly the 3 gloads; stores
//    are NEVER drained in-loop. fp64-fallback loads only tighten the wait.
//  - Select (R9/R10, proven): pk-max tree + DPP quad-max + eps-match mask;
//    popcount==1 -> ctz; else quad-uniform exact fp64 fallback.

typedef float v2f __attribute__((ext_vector_type(2)));

#define BATCH 32768
#define DIM   768
#define K_CB  32
#define D_SUB 6
#define BROWS 16               // rows per block
#define RSTG  8                // rows per LDS stage
#define NSTG  (BROWS/RSTG)     // 2 stages
#define HALFF 384              // floats per half row (64 m * 6)
#define STGF  (RSTG*HALFF)     // 3072 floats = 12 KiB per buffer
#define EPS_TIE 1e-5f

#define DPP_XOR1 0xB1          // quad_perm [1,0,3,2]
#define DPP_XOR2 0x4E          // quad_perm [2,3,0,1]

template<int CTRL>
__device__ __forceinline__ float dppf(float v) {
    return __int_as_float(__builtin_amdgcn_update_dpp(
        0, __float_as_int(v), CTRL, 0xF, 0xF, true));
}
template<int CTRL>
__device__ __forceinline__ int dppi(int v) {
    return __builtin_amdgcn_update_dpp(0, v, CTRL, 0xF, 0xF, true);
}

// Async global->LDS, 16 B per lane. size must be a literal (m97).
__device__ __forceinline__ void glds16(const float* g, float* l) {
    __builtin_amdgcn_global_load_lds(
        (const __attribute__((address_space(1))) void*)g,
        (__attribute__((address_space(3))) void*)l,
        16, 0, 0);
}

__global__ __launch_bounds__(256, 4)
void pq_head_kernel(const float* __restrict__ x,
                    const float* __restrict__ cb,
                    float* __restrict__ out) {
    __shared__ float xs[2][STGF];   // 24 KiB double buffer

    const int t     = threadIdx.x;
    const int kq    = t & 3;        // k-quarter (lane within quad)
    const int mloc  = t >> 2;       // 0..63
    const int mhalf = blockIdx.y;   // 0/1
    const int m     = mhalf * 64 + mloc;
    const int b0    = blockIdx.x * BROWS;

    const float* xh = x   + (size_t)mhalf * HALFF;  // half-row base
    float*       oh = out + (size_t)mhalf * HALFF;

    // Stage-invariant (row, col) for the coalesced stage load.
    int pr[3], pc[3];
    #pragma unroll
    for (int i = 0; i < 3; ++i) {
        int f = (i * 256 + t) * 4;          // float index within stage (<3072)
        pr[i] = f / HALFF;
        pc[i] = f - pr[i] * HALFF;
    }

    // Issue stage-0 loads FIRST so their HBM latency overlaps the cb prologue.
    #pragma unroll
    for (int i = 0; i < 3; ++i)
        glds16(xh + (size_t)(b0 + pr[i]) * DIM + pc[i],
               &xs[0][(i * 256 + t) * 4]);

    // Load this lane's 8 codebook rows (48 floats, 192-B aligned) and pack
    // code-pairs into v2f: cpk[p][e] = (cb[2p][e], cb[2p+1][e]).
    v2f cpk[4][D_SUB];
    {
        float cc[48];
        const float4* cb4 = reinterpret_cast<const float4*>(
            cb + ((size_t)m * K_CB + (size_t)kq * 8) * D_SUB);
        #pragma unroll
        for (int i = 0; i < 12; ++i) {
            float4 v = cb4[i];
            cc[4*i+0]=v.x; cc[4*i+1]=v.y; cc[4*i+2]=v.z; cc[4*i+3]=v.w;
        }
        #pragma unroll
        for (int p = 0; p < 4; ++p)
            #pragma unroll
            for (int e = 0; e < D_SUB; ++e)
                cpk[p][e] = (v2f){cc[(2*p)*D_SUB + e], cc[(2*p+1)*D_SUB + e]};
    }

    __syncthreads();   // prologue: full drain (vmcnt(0)) + barrier — stage 0 ready

    for (int s = 0; s < NSTG; ++s) {
        float* buf = xs[s & 1];

        // Issue next stage's direct-to-LDS loads into the OTHER buffer.
        // (Safe: all waves finished reading it before the previous barrier.)
        if (s + 1 < NSTG) {
            int rb = b0 + (s + 1) * RSTG;
            #pragma unroll
            for (int i = 0; i < 3; ++i)
                glds16(xh + (size_t)(rb + pr[i]) * DIM + pc[i],
                       &xs[(s + 1) & 1][(i * 256 + t) * 4]);
        }

        // ---- phase A: 8 winner computations -> kg8[] ----
        int kg8[RSTG];
        #pragma unroll
        for (int r = 0; r < RSTG; ++r) {
            const float* xr = &buf[r * HALFF + mloc * D_SUB];  // quad-broadcast
            float2 x01 = *reinterpret_cast<const float2*>(xr);
            float2 x23 = *reinterpret_cast<const float2*>(xr + 2);
            float2 x45 = *reinterpret_cast<const float2*>(xr + 4);
            float xv[6] = {x01.x, x01.y, x23.x, x23.y, x45.x, x45.y};
            v2f xxe[6];
            #pragma unroll
            for (int e = 0; e < 6; ++e) xxe[e] = (v2f){xv[e], xv[e]};

            // 8 packed dots, kept live in acc[4].
            v2f acc[4];
            #pragma unroll
            for (int p = 0; p < 4; ++p) {
                v2f a = cpk[p][0] * xxe[0];
                #pragma unroll
                for (int e = 1; e < 6; ++e)
                    a = __builtin_elementwise_fma(cpk[p][e], xxe[e], a);
                acc[p] = a;
            }

            // Quad max via pk-max tree + 2 DPP merges (pure VALU, ~8 ops).
            v2f t0 = __builtin_elementwise_max(acc[0], acc[1]);
            v2f t1 = __builtin_elementwise_max(acc[2], acc[3]);
            v2f t2 = __builtin_elementwise_max(t0, t1);
            float best1 = fmaxf(t2.x, t2.y);
            best1 = fmaxf(best1, dppf<DPP_XOR1>(best1));
            best1 = fmaxf(best1, dppf<DPP_XOR2>(best1));

            // Epsilon-match mask: bit j set iff dot_j > best1 - 1e-5.
            const float thr = best1 - EPS_TIE;
            int msk = 0;
            #pragma unroll
            for (int p = 0; p < 4; ++p) {
                if (acc[p].x > thr) msk |= 1 << (2*p);
                if (acc[p].y > thr) msk |= 1 << (2*p+1);
            }
            int full = msk << (kq * 8);
            full |= dppi<DPP_XOR1>(full);
            full |= dppi<DPP_XOR2>(full);   // quad-uniform 32-bit mask

            int kg;
            if (__builtin_popcount(full) == 1) {
                // Unique near-max => it IS the strict argmax.
                kg = __builtin_ctz(full);
            } else {
                // Ambiguous within 1e-5 (incl. exact ties): exact fp64 argmax,
                // first-wins — matches jnp.argmax. Quad-uniform branch.
                const float* crow = cb + (size_t)m * K_CB * D_SUB;
                double db = -1e300; int dkg = 0;
                for (int k2 = 0; k2 < K_CB; ++k2) {
                    double sa = 0.0;
                    for (int e = 0; e < 6; ++e)
                        sa = fma((double)crow[k2*6+e], (double)xv[e], sa);
                    if (sa > db) { db = sa; dkg = k2; }
                }
                kg = dkg;
            }
            kg8[r] = kg;
        }

        // ---- phase B: 8 independent winner gathers (cb is L1/L2-hot) ----
        const bool act = (kq < 3);
        float2 gv[RSTG];
        if (act) {
            #pragma unroll
            for (int r = 0; r < RSTG; ++r)
                gv[r] = *(reinterpret_cast<const float2*>(
                    cb + ((size_t)m * K_CB + (size_t)kg8[r]) * D_SUB) + kq);
        }

        __builtin_amdgcn_sched_barrier(0);  // keep all gathers above all stores

        // ---- phase C: 8 coalesced float2 stores (48/64 lanes -> full lines) ----
        if (act) {
            #pragma unroll
            for (int r = 0; r < RSTG; ++r) {
                float* dst = oh + (size_t)(b0 + s * RSTG + r) * DIM + mloc * D_SUB;
                *(reinterpret_cast<float2*>(dst) + kq) = gv[r];
            }
        }

        // Counted-vmcnt stage boundary: retire ONLY the 3 gloads (oldest);
        // gathers/stores (>=16 younger ops) may stay in flight across it.
        if (s + 1 < NSTG) {
            asm volatile("s_waitcnt vmcnt(16)" ::: "memory");
            __builtin_amdgcn_s_barrier();
            __builtin_amdgcn_sched_barrier(0);
        }
    }
}

extern "C" void kernel_launch(void* const* d_in, const int* in_sizes, int n_in,
                              void* d_out, int out_size, void* d_ws, size_t ws_size,
                              hipStream_t stream) {
    const float* x  = (const float*)d_in[0];   // (32768, 768) fp32
    const float* cb = (const float*)d_in[1];   // (128, 32, 6) fp32
    float* out = (float*)d_out;                // (32768, 768) fp32

    dim3 grid(BATCH / BROWS, 2);   // 2048 x 2 = 4096 blocks
    dim3 block(256);               // 64 m x 4 k-quarters
    hipLaunchKernelGGL(pq_head_kernel, grid, block, 0, stream, x, cb, out);
}

// Round 7
// 218.185 us; speedup vs baseline: 1.2502x; 1.0671x over previous
//
#include <hip/hip_runtime.h>
#include <float.h>

// PQHead forward: out[b, m*6+d] = codebooks[m, argmax_k dot(x[b,m,:], cb[m,k,:]), d]
// (straight-through estimator: forward value of quant is exactly `discrete`)
//
// R13: double TLP, keep the sweep shape. Evidence chain:
//  - R7 (no barriers) = 122us, R10 (barriers) = 102.5us, R12 (counted
//    vmcnt) = 112.7us -> barrier drain is NOT the stall.
//  - Occupancy 32% => ~10 waves/CU, wave lifetime ~16us vs ~2.2us VALU
//    issue: latency-underhiding from TLP shortage. Residency capped by
//    24 KB LDS + 4-wave blocks.
//  - Fix: BROWS 16->8, ONE 12 KB buffer, ONE barrier, 8192 blocks.
//    Sliding-window sweep preserved (resident window ~49 MB, same
//    fraction). Residency cap: 8 blocks/CU if VGPR<=64 (no pf regs, no
//    double buffer -> pressure drops).
//  - x staged direct-to-LDS (glds16) issued BEFORE cb prologue so HBM
//    latency hides under it; single __syncthreads() drains it.
//  - Select (R9/R10, proven): pk-max tree + DPP quad-max + eps-mask;
//    popcount==1 -> ctz; else quad-uniform exact fp64 fallback.
//  - Phase B/C (R6/R10, proven): 8 batched gathers; sched_barrier;
//    8 coalesced float2 stores.
//  - TRIPWIRES: WRITE_SIZE must stay ~98.3 MB; VGPR <= 64.

typedef float v2f __attribute__((ext_vector_type(2)));

#define BATCH 32768
#define DIM   768
#define K_CB  32
#define D_SUB 6
#define BROWS 8                // rows per block (one stage)
#define HALFF 384              // floats per half row (64 m * 6)
#define STGF  (BROWS*HALFF)    // 3072 floats = 12 KiB
#define EPS_TIE 1e-5f

#define DPP_XOR1 0xB1          // quad_perm [1,0,3,2]
#define DPP_XOR2 0x4E          // quad_perm [2,3,0,1]

template<int CTRL>
__device__ __forceinline__ float dppf(float v) {
    return __int_as_float(__builtin_amdgcn_update_dpp(
        0, __float_as_int(v), CTRL, 0xF, 0xF, true));
}
template<int CTRL>
__device__ __forceinline__ int dppi(int v) {
    return __builtin_amdgcn_update_dpp(0, v, CTRL, 0xF, 0xF, true);
}

// Async global->LDS, 16 B per lane. size must be a literal constant.
__device__ __forceinline__ void glds16(const float* g, float* l) {
    __builtin_amdgcn_global_load_lds(
        (const __attribute__((address_space(1))) void*)g,
        (__attribute__((address_space(3))) void*)l,
        16, 0, 0);
}

__global__ __launch_bounds__(256, 4)
void pq_head_kernel(const float* __restrict__ x,
                    const float* __restrict__ cb,
                    float* __restrict__ out) {
    __shared__ float xs[STGF];      // 12 KiB single buffer

    const int t     = threadIdx.x;
    const int kq    = t & 3;        // k-quarter (lane within quad)
    const int mloc  = t >> 2;       // 0..63
    const int mhalf = blockIdx.y;   // 0/1
    const int m     = mhalf * 64 + mloc;
    const int b0    = blockIdx.x * BROWS;

    const float* xh = x   + (size_t)mhalf * HALFF;  // half-row base
    float*       oh = out + (size_t)mhalf * HALFF;

    // Issue the whole x stage (3 x 16B/lane = 12 KiB) FIRST; its HBM/L3
    // latency overlaps the cb prologue below. LDS dest is linear in lane
    // ((i*256+t)*16 B) -> matches the HW wave-uniform-base + lane*16 rule.
    #pragma unroll
    for (int i = 0; i < 3; ++i) {
        int f = (i * 256 + t) * 4;          // float index within stage (<3072)
        int r = f / HALFF;
        int c = f - r * HALFF;
        glds16(xh + (size_t)(b0 + r) * DIM + c, &xs[f]);
    }

    // Load this lane's 8 codebook rows (48 floats, 192-B aligned) and pack
    // code-pairs into v2f: cpk[p][e] = (cb[2p][e], cb[2p+1][e]).
    v2f cpk[4][D_SUB];
    {
        float cc[48];
        const float4* cb4 = reinterpret_cast<const float4*>(
            cb + ((size_t)m * K_CB + (size_t)kq * 8) * D_SUB);
        #pragma unroll
        for (int i = 0; i < 12; ++i) {
            float4 v = cb4[i];
            cc[4*i+0]=v.x; cc[4*i+1]=v.y; cc[4*i+2]=v.z; cc[4*i+3]=v.w;
        }
        #pragma unroll
        for (int p = 0; p < 4; ++p)
            #pragma unroll
            for (int e = 0; e < D_SUB; ++e)
                cpk[p][e] = (v2f){cc[(2*p)*D_SUB + e], cc[(2*p+1)*D_SUB + e]};
    }

    __syncthreads();   // drains glds (vmcnt 0) + barrier: stage ready

    // ---- phase A: 8 winner computations -> kg8[] ----
    int kg8[BROWS];
    #pragma unroll
    for (int r = 0; r < BROWS; ++r) {
        const float* xr = &xs[r * HALFF + mloc * D_SUB];   // quad-broadcast
        float2 x01 = *reinterpret_cast<const float2*>(xr);
        float2 x23 = *reinterpret_cast<const float2*>(xr + 2);
        float2 x45 = *reinterpret_cast<const float2*>(xr + 4);
        float xv[6] = {x01.x, x01.y, x23.x, x23.y, x45.x, x45.y};
        v2f xxe[6];
        #pragma unroll
        for (int e = 0; e < 6; ++e) xxe[e] = (v2f){xv[e], xv[e]};

        // 8 packed dots, kept live in acc[4].
        v2f acc[4];
        #pragma unroll
        for (int p = 0; p < 4; ++p) {
            v2f a = cpk[p][0] * xxe[0];
            #pragma unroll
            for (int e = 1; e < 6; ++e)
                a = __builtin_elementwise_fma(cpk[p][e], xxe[e], a);
            acc[p] = a;
        }

        // Quad max via pk-max tree + 2 DPP merges (pure VALU, ~8 ops).
        v2f t0 = __builtin_elementwise_max(acc[0], acc[1]);
        v2f t1 = __builtin_elementwise_max(acc[2], acc[3]);
        v2f t2 = __builtin_elementwise_max(t0, t1);
        float best1 = fmaxf(t2.x, t2.y);
        best1 = fmaxf(best1, dppf<DPP_XOR1>(best1));
        best1 = fmaxf(best1, dppf<DPP_XOR2>(best1));

        // Epsilon-match mask: bit j set iff dot_j > best1 - 1e-5.
        const float thr = best1 - EPS_TIE;
        int msk = 0;
        #pragma unroll
        for (int p = 0; p < 4; ++p) {
            if (acc[p].x > thr) msk |= 1 << (2*p);
            if (acc[p].y > thr) msk |= 1 << (2*p+1);
        }
        int full = msk << (kq * 8);
        full |= dppi<DPP_XOR1>(full);
        full |= dppi<DPP_XOR2>(full);   // quad-uniform 32-bit mask

        int kg;
        if (__builtin_popcount(full) == 1) {
            // Unique near-max => it IS the strict argmax.
            kg = __builtin_ctz(full);
        } else {
            // Ambiguous within 1e-5 (incl. exact ties): exact fp64 argmax,
            // first-wins — matches jnp.argmax. Quad-uniform branch.
            const float* crow = cb + (size_t)m * K_CB * D_SUB;
            double db = -1e300; int dkg = 0;
            for (int k2 = 0; k2 < K_CB; ++k2) {
                double sa = 0.0;
                for (int e = 0; e < 6; ++e)
                    sa = fma((double)crow[k2*6+e], (double)xv[e], sa);
                if (sa > db) { db = sa; dkg = k2; }
            }
            kg = dkg;
        }
        kg8[r] = kg;
    }

    // ---- phase B: 8 independent winner gathers (cb is L1/L2-hot) ----
    const bool act = (kq < 3);
    float2 gv[BROWS];
    if (act) {
        #pragma unroll
        for (int r = 0; r < BROWS; ++r)
            gv[r] = *(reinterpret_cast<const float2*>(
                cb + ((size_t)m * K_CB + (size_t)kg8[r]) * D_SUB) + kq);
    }

    __builtin_amdgcn_sched_barrier(0);  // keep all gathers above all stores

    // ---- phase C: 8 coalesced float2 stores (48/64 lanes -> full lines) ----
    if (act) {
        #pragma unroll
        for (int r = 0; r < BROWS; ++r) {
            float* dst = oh + (size_t)(b0 + r) * DIM + mloc * D_SUB;
            *(reinterpret_cast<float2*>(dst) + kq) = gv[r];
        }
    }
}

extern "C" void kernel_launch(void* const* d_in, const int* in_sizes, int n_in,
                              void* d_out, int out_size, void* d_ws, size_t ws_size,
                              hipStream_t stream) {
    const float* x  = (const float*)d_in[0];   // (32768, 768) fp32
    const float* cb = (const float*)d_in[1];   // (128, 32, 6) fp32
    float* out = (float*)d_out;                // (32768, 768) fp32

    dim3 grid(BATCH / BROWS, 2);   // 4096 x 2 = 8192 blocks
    dim3 block(256);               // 64 m x 4 k-quarters
    hipLaunchKernelGGL(pq_head_kernel, grid, block, 0, stream, x, cb, out);
}

// Round 8
// 212.367 us; speedup vs baseline: 1.2845x; 1.0274x over previous
//
#include <hip/hip_runtime.h>
#include <float.h>

// PQHead forward: out[b, m*6+d] = codebooks[m, argmax_k dot(x[b,m,:], cb[m,k,:]), d]
// (straight-through estimator: forward value of quant is exactly `discrete`)
//
// R14: coalesce the cb prologue via a workspace-rearranged codebook.
//  - R13 post-mortem: occupancy ~31% is an EQUILIBRIUM (R9 hit 57% when
//    waves slowed), not a cap. Line-request arithmetic: cb prologue's 12
//    dwordx4 at lane-stride 192 B touch 64 lines/instr = 768 lines/wave;
//    total ~1200 lines/wave -> ~64% TA busy at 1 line/cy/CU. TA is the
//    saturated pipe (explains schedule-invariant ~100-120us and why the
//    VALU diet barely moved wall).
//  - Fix: pq_prep kernel (same stream, graph-safe) rearranges cb into
//    d_ws in exact wave-load order cw[g=mhalf*4+w][i=0..11][l=0..63];
//    main prologue = 12 fully-coalesced dwordx4 (16 lines each):
//    768 -> 192 lines/wave, zero over-read. cc[] layout unchanged.
//  - Everything else byte-identical to R13 (BROWS=8, 8192 blocks, glds16
//    x staging, one barrier, dieted select, batched gathers, coalesced
//    float2 stores). Host fallback to R13 load path if ws too small.
//  - TRIPWIRES: WRITE ~98.4 MB, FETCH ~50 MB, VGPR <= 64.

typedef float v2f __attribute__((ext_vector_type(2)));

#define BATCH 32768
#define DIM   768
#define K_CB  32
#define D_SUB 6
#define BROWS 8                // rows per block (one stage)
#define HALFF 384              // floats per half row (64 m * 6)
#define STGF  (BROWS*HALFF)    // 3072 floats = 12 KiB
#define EPS_TIE 1e-5f
#define CW_PIECES 6144         // 8 groups * 12 instr * 64 lanes (float4 units)
#define CW_BYTES  (CW_PIECES*16)

#define DPP_XOR1 0xB1          // quad_perm [1,0,3,2]
#define DPP_XOR2 0x4E          // quad_perm [2,3,0,1]

template<int CTRL>
__device__ __forceinline__ float dppf(float v) {
    return __int_as_float(__builtin_amdgcn_update_dpp(
        0, __float_as_int(v), CTRL, 0xF, 0xF, true));
}
template<int CTRL>
__device__ __forceinline__ int dppi(int v) {
    return __builtin_amdgcn_update_dpp(0, v, CTRL, 0xF, 0xF, true);
}

// Async global->LDS, 16 B per lane. size must be a literal constant.
__device__ __forceinline__ void glds16(const float* g, float* l) {
    __builtin_amdgcn_global_load_lds(
        (const __attribute__((address_space(1))) void*)g,
        (__attribute__((address_space(3))) void*)l,
        16, 0, 0);
}

// Rearrange cb (128*32*6 fp32 = 96 KiB) into wave-load order:
// cw[g*768 + i*64 + l] = float4 at cb[m*192 + kq*48 + 4i], where
// g = mhalf*4 + w, m = (g>>2)*64 + (g&3)*16 + (l>>2), kq = l&3.
__global__ void pq_prep(const float* __restrict__ cb,
                        float4* __restrict__ cw) {
    int P = blockIdx.x * 256 + threadIdx.x;   // 0..6143
    if (P >= CW_PIECES) return;
    int g = P / 768;
    int q = P - g * 768;
    int i = q >> 6;
    int l = q & 63;
    int m  = (g >> 2) * 64 + (g & 3) * 16 + (l >> 2);
    int kq = l & 3;
    cw[P] = *reinterpret_cast<const float4*>(cb + m * 192 + kq * 48 + 4 * i);
}

template<int USE_WS>
__global__ __launch_bounds__(256, 4)
void pq_head_kernel(const float* __restrict__ x,
                    const float* __restrict__ cb,
                    const float4* __restrict__ cw,
                    float* __restrict__ out) {
    __shared__ float xs[STGF];      // 12 KiB single buffer

    const int t     = threadIdx.x;
    const int kq    = t & 3;        // k-quarter (lane within quad)
    const int mloc  = t >> 2;       // 0..63
    const int mhalf = blockIdx.y;   // 0/1
    const int m     = mhalf * 64 + mloc;
    const int b0    = blockIdx.x * BROWS;

    const float* xh = x   + (size_t)mhalf * HALFF;  // half-row base
    float*       oh = out + (size_t)mhalf * HALFF;

    // Issue the whole x stage (3 x 16B/lane = 12 KiB) FIRST; its HBM/L3
    // latency overlaps the cb prologue below. LDS dest is linear in lane.
    #pragma unroll
    for (int i = 0; i < 3; ++i) {
        int f = (i * 256 + t) * 4;          // float index within stage (<3072)
        int r = f / HALFF;
        int c = f - r * HALFF;
        glds16(xh + (size_t)(b0 + r) * DIM + c, &xs[f]);
    }

    // Load this lane's 8 codebook rows (48 floats) and pack code-pairs
    // into v2f: cpk[p][e] = (cb[2p][e], cb[2p+1][e]).
    v2f cpk[4][D_SUB];
    {
        float cc[48];
        if constexpr (USE_WS) {
            // Wave-load-order copy: instr i reads 64 consecutive float4s
            // -> 16 lines/instr instead of 64 (the R14 fix).
            const float4* wp = cw + ((size_t)mhalf * 4 + (t >> 6)) * 768 + (t & 63);
            #pragma unroll
            for (int i = 0; i < 12; ++i) {
                float4 v = wp[i * 64];
                cc[4*i+0]=v.x; cc[4*i+1]=v.y; cc[4*i+2]=v.z; cc[4*i+3]=v.w;
            }
        } else {
            const float4* cb4 = reinterpret_cast<const float4*>(
                cb + ((size_t)m * K_CB + (size_t)kq * 8) * D_SUB);
            #pragma unroll
            for (int i = 0; i < 12; ++i) {
                float4 v = cb4[i];
                cc[4*i+0]=v.x; cc[4*i+1]=v.y; cc[4*i+2]=v.z; cc[4*i+3]=v.w;
            }
        }
        #pragma unroll
        for (int p = 0; p < 4; ++p)
            #pragma unroll
            for (int e = 0; e < D_SUB; ++e)
                cpk[p][e] = (v2f){cc[(2*p)*D_SUB + e], cc[(2*p+1)*D_SUB + e]};
    }

    __syncthreads();   // drains glds (vmcnt 0) + barrier: stage ready

    // ---- phase A: 8 winner computations -> kg8[] ----
    int kg8[BROWS];
    #pragma unroll
    for (int r = 0; r < BROWS; ++r) {
        const float* xr = &xs[r * HALFF + mloc * D_SUB];   // quad-broadcast
        float2 x01 = *reinterpret_cast<const float2*>(xr);
        float2 x23 = *reinterpret_cast<const float2*>(xr + 2);
        float2 x45 = *reinterpret_cast<const float2*>(xr + 4);
        float xv[6] = {x01.x, x01.y, x23.x, x23.y, x45.x, x45.y};
        v2f xxe[6];
        #pragma unroll
        for (int e = 0; e < 6; ++e) xxe[e] = (v2f){xv[e], xv[e]};

        // 8 packed dots, kept live in acc[4].
        v2f acc[4];
        #pragma unroll
        for (int p = 0; p < 4; ++p) {
            v2f a = cpk[p][0] * xxe[0];
            #pragma unroll
            for (int e = 1; e < 6; ++e)
                a = __builtin_elementwise_fma(cpk[p][e], xxe[e], a);
            acc[p] = a;
        }

        // Quad max via pk-max tree + 2 DPP merges (pure VALU, ~8 ops).
        v2f t0 = __builtin_elementwise_max(acc[0], acc[1]);
        v2f t1 = __builtin_elementwise_max(acc[2], acc[3]);
        v2f t2 = __builtin_elementwise_max(t0, t1);
        float best1 = fmaxf(t2.x, t2.y);
        best1 = fmaxf(best1, dppf<DPP_XOR1>(best1));
        best1 = fmaxf(best1, dppf<DPP_XOR2>(best1));

        // Epsilon-match mask: bit j set iff dot_j > best1 - 1e-5.
        const float thr = best1 - EPS_TIE;
        int msk = 0;
        #pragma unroll
        for (int p = 0; p < 4; ++p) {
            if (acc[p].x > thr) msk |= 1 << (2*p);
            if (acc[p].y > thr) msk |= 1 << (2*p+1);
        }
        int full = msk << (kq * 8);
        full |= dppi<DPP_XOR1>(full);
        full |= dppi<DPP_XOR2>(full);   // quad-uniform 32-bit mask

        int kg;
        if (__builtin_popcount(full) == 1) {
            // Unique near-max => it IS the strict argmax.
            kg = __builtin_ctz(full);
        } else {
            // Ambiguous within 1e-5 (incl. exact ties): exact fp64 argmax,
            // first-wins — matches jnp.argmax. Quad-uniform branch.
            const float* crow = cb + (size_t)m * K_CB * D_SUB;
            double db = -1e300; int dkg = 0;
            for (int k2 = 0; k2 < K_CB; ++k2) {
                double sa = 0.0;
                for (int e = 0; e < 6; ++e)
                    sa = fma((double)crow[k2*6+e], (double)xv[e], sa);
                if (sa > db) { db = sa; dkg = k2; }
            }
            kg = dkg;
        }
        kg8[r] = kg;
    }

    // ---- phase B: 8 independent winner gathers (cb is L1/L2-hot) ----
    const bool act = (kq < 3);
    float2 gv[BROWS];
    if (act) {
        #pragma unroll
        for (int r = 0; r < BROWS; ++r)
            gv[r] = *(reinterpret_cast<const float2*>(
                cb + ((size_t)m * K_CB + (size_t)kg8[r]) * D_SUB) + kq);
    }

    __builtin_amdgcn_sched_barrier(0);  // keep all gathers above all stores

    // ---- phase C: 8 coalesced float2 stores (48/64 lanes -> full lines) ----
    if (act) {
        #pragma unroll
        for (int r = 0; r < BROWS; ++r) {
            float* dst = oh + (size_t)(b0 + r) * DIM + mloc * D_SUB;
            *(reinterpret_cast<float2*>(dst) + kq) = gv[r];
        }
    }
}

extern "C" void kernel_launch(void* const* d_in, const int* in_sizes, int n_in,
                              void* d_out, int out_size, void* d_ws, size_t ws_size,
                              hipStream_t stream) {
    const float* x  = (const float*)d_in[0];   // (32768, 768) fp32
    const float* cb = (const float*)d_in[1];   // (128, 32, 6) fp32
    float* out = (float*)d_out;                // (32768, 768) fp32

    dim3 grid(BATCH / BROWS, 2);   // 4096 x 2 = 8192 blocks
    dim3 block(256);               // 64 m x 4 k-quarters

    if (ws_size >= (size_t)CW_BYTES) {
        float4* cw = (float4*)d_ws;
        hipLaunchKernelGGL(pq_prep, dim3(CW_PIECES / 256), dim3(256), 0, stream,
                           cb, cw);
        hipLaunchKernelGGL(pq_head_kernel<1>, grid, block, 0, stream,
                           x, cb, cw, out);
    } else {
        hipLaunchKernelGGL(pq_head_kernel<0>, grid, block, 0, stream,
                           x, cb, (const float4*)nullptr, out);
    }
}